// Round 1
// 415.851 us; speedup vs baseline: 1.1136x; 1.1136x over previous
//
#include <hip/hip_runtime.h>
#include <type_traits>

// Problem constants: H=16, D=64, DM=1024, L=256, B=64, CHUNK=64, SCALE=1/8.

typedef short v8s __attribute__((ext_vector_type(8)));
typedef float v4f __attribute__((ext_vector_type(4)));

__device__ __forceinline__ float bf2f(short s) {
    unsigned int u = ((unsigned int)(unsigned short)s) << 16;
    float f;
    __builtin_memcpy(&f, &u, 4);
    return f;
}
__device__ __forceinline__ short f2bf(float f) {
    unsigned int u;
    __builtin_memcpy(&u, &f, 4);
    u = u + 0x7fffu + ((u >> 16) & 1u);   // RNE
    return (short)(u >> 16);
}

// async global->LDS, 16B per lane; LDS dest = wave-uniform base + lane*16
__device__ __forceinline__ void load_lds16(const short* g, short* l) {
    __builtin_amdgcn_global_load_lds((const __attribute__((address_space(1))) void*)g,
                                     (__attribute__((address_space(3))) void*)l, 16, 0, 0);
}

// ---------------- fp32 -> bf16 conversion (vectorized x4) ----------------
__global__ void __launch_bounds__(256)
cvt_bf16(const float* __restrict__ in, short* __restrict__ out, int n4) {
    int i = blockIdx.x * 256 + threadIdx.x;
    if (i >= n4) return;
    float4 v = ((const float4*)in)[i];
    short4 o;
    o.x = f2bf(v.x); o.y = f2bf(v.y); o.z = f2bf(v.z); o.w = f2bf(v.w);
    ((short4*)out)[i] = o;
}

// ---------------- bf16 MFMA GEMM:  C[M,N] = A[M,K] * B[N,K]^T ----------------
// 256x256 tile, BK=64, 8 waves (2Mx4N), 512 threads. 8-phase schedule with
// counted vmcnt (T3+T4), XOR LDS swizzle via pre-swizzled global source (T2),
// setprio around MFMA clusters (T5), XCD-aware block swizzle (T1).
// Requires: M%256==0, N%256==0, K%128==0, grid size %8==0 (true for our shapes).
template <typename OutT>
__global__ void __launch_bounds__(512, 2)
gemm_nt(const short* __restrict__ Ap, const short* __restrict__ Bp,
        OutT* __restrict__ C, int M, int N, int K) {
    // [buf][mat(0=A,1=B)][256 rows][64 cols]
    __shared__ __align__(16) short lds[2][2][256 * 64];

    const int tid = threadIdx.x;
    const int w = tid >> 6, lane = tid & 63;
    const int wm = w >> 2, wn = w & 3;          // wave tile: 128 rows x 64 cols
    const int lq = lane >> 4, lr = lane & 15;
    const int asw = (lr & 7) * 8;               // read-side XOR swizzle (shorts)
    const int rr = tid >> 3;                    // staging: row within 64-row chunk
    const int scol = ((tid & 7) * 8) ^ ((rr & 7) * 8);  // pre-swizzled source col

    // XCD-aware bijective block swizzle (nwg % 8 == 0 for our launches)
    int bid = blockIdx.y * gridDim.x + blockIdx.x;
    int nwg = gridDim.x * gridDim.y;
    int swz = (bid & 7) * (nwg >> 3) + (bid >> 3);
    int bm = swz % gridDim.x, bn = swz / gridDim.x;

    v4f acc[8][4] = {};
    v8s a[4][2];        // A frags for current qm (4 m-frags x 2 k-halves)
    v8s b[2][2][2];     // B frags for both qn (qn x 2 n-frags x 2 k-halves)

    const int NT = K >> 6;          // K-tiles of 64
    const int nIter = NT >> 1;      // 2 K-tiles per iteration

#define BAR_() do { asm volatile("" ::: "memory"); __builtin_amdgcn_s_barrier(); asm volatile("" ::: "memory"); } while (0)
#define VMCNT4_() asm volatile("s_waitcnt vmcnt(4)" ::: "memory")
    // stage one half-tile (128 rows x 64 cols) = 2 x global_load_lds(16B) per thread
#define STAGE_(MAT, BUF, HALF, KT) do { \
        const short* g_ = ((MAT) ? Bp : Ap) + \
            (long)(((MAT) ? bn : bm) * 256 + (HALF) * 128 + rr) * K + (KT) * 64 + scol; \
        short* l_ = &lds[BUF][MAT][(HALF) * 8192] + w * 512; \
        load_lds16(g_, l_); \
        load_lds16(g_ + (long)64 * K, l_ + 4096); \
    } while (0)
    // A fragment loads for quadrant QM from buffer BUF (8 x ds_read_b128)
#define LDA_(QM, BUF) do { \
        _Pragma("unroll") \
        for (int mi = 0; mi < 4; ++mi) { \
            const short* pa_ = &lds[BUF][0][(wm * 128 + (QM) * 64 + mi * 16 + lr) * 64]; \
            a[mi][0] = *(const v8s*)&pa_[(lq * 8) ^ asw]; \
            a[mi][1] = *(const v8s*)&pa_[(32 + lq * 8) ^ asw]; \
        } \
    } while (0)
    // B fragment loads for quadrant QN from buffer BUF (4 x ds_read_b128)
#define LDB_(QN, BUF) do { \
        _Pragma("unroll") \
        for (int ni = 0; ni < 2; ++ni) { \
            const short* pb_ = &lds[BUF][1][(wn * 64 + (QN) * 32 + ni * 16 + lr) * 64]; \
            b[QN][ni][0] = *(const v8s*)&pb_[(lq * 8) ^ asw]; \
            b[QN][ni][1] = *(const v8s*)&pb_[(32 + lq * 8) ^ asw]; \
        } \
    } while (0)
    // one C-quadrant x K=64: 16 MFMA, prioritized
#define MFMA_(QM, QN) do { \
        __builtin_amdgcn_s_setprio(1); \
        _Pragma("unroll") \
        for (int kk = 0; kk < 2; ++kk) \
            _Pragma("unroll") \
            for (int mi = 0; mi < 4; ++mi) \
                _Pragma("unroll") \
                for (int ni = 0; ni < 2; ++ni) \
                    acc[(QM) * 4 + mi][(QN) * 2 + ni] = __builtin_amdgcn_mfma_f32_16x16x32_bf16( \
                        a[mi][kk], b[QN][ni][kk], acc[(QM) * 4 + mi][(QN) * 2 + ni], 0, 0, 0); \
        __builtin_amdgcn_s_setprio(0); \
    } while (0)

    // ---- prologue: tile0 (all 4 half-tiles) into buf0, tile1.B into buf1 ----
    STAGE_(1, 0, 0, 0);
    STAGE_(1, 0, 1, 0);
    STAGE_(0, 0, 0, 0);
    STAGE_(0, 0, 1, 0);
    STAGE_(1, 1, 0, 1);
    STAGE_(1, 1, 1, 1);
    VMCNT4_();          // tile0's 8 loads landed; tile1.B (4) may stay in flight
    BAR_();

    // ---- main loop: 8 phases per iteration, 2 K-tiles ----
    for (int it = 0; it < nIter; ++it) {
        const int t = 2 * it;
        const int t1 = t + 1;
        int t2 = t + 2; if (t2 >= NT) t2 -= NT;   // wrapped tail staging keeps
        int t3 = t + 3; if (t3 >= NT) t3 -= NT;   // vmcnt counts exact (data unused)

        // ph0: compute buf0 (qm0,qn0); stage buf1.A.h0 <- t1
        LDA_(0, 0); LDB_(0, 0);
        STAGE_(0, 1, 0, t1);
        BAR_(); MFMA_(0, 0); BAR_();
        // ph1: (qm0,qn1); stage buf1.A.h1 <- t1
        LDB_(1, 0);
        STAGE_(0, 1, 1, t1);
        BAR_(); MFMA_(0, 1); BAR_();
        // ph2: (qm1,qn0); stage buf0.B.h0 <- t2   (buf0.B dead after ph1)
        LDA_(1, 0);
        STAGE_(1, 0, 0, t2);
        BAR_(); MFMA_(1, 0); BAR_();
        // ph3: (qm1,qn1); stage buf0.B.h1 <- t2; counted wait for tile t1
        STAGE_(1, 0, 1, t2);
        VMCNT4_();
        BAR_(); MFMA_(1, 1); BAR_();
        // ph4: compute buf1 (qm0,qn0); stage buf0.A.h0 <- t2  (buf0.A dead after ph2)
        LDA_(0, 1); LDB_(0, 1);
        STAGE_(0, 0, 0, t2);
        BAR_(); MFMA_(0, 0); BAR_();
        // ph5: (qm0,qn1); stage buf0.A.h1 <- t2
        LDB_(1, 1);
        STAGE_(0, 0, 1, t2);
        BAR_(); MFMA_(0, 1); BAR_();
        // ph6: (qm1,qn0); stage buf1.B.h0 <- t3   (buf1.B dead after ph5)
        LDA_(1, 1);
        STAGE_(1, 1, 0, t3);
        BAR_(); MFMA_(1, 0); BAR_();
        // ph7: (qm1,qn1); stage buf1.B.h1 <- t3; counted wait for tile t2
        STAGE_(1, 1, 1, t3);
        VMCNT4_();
        BAR_(); MFMA_(1, 1); BAR_();
    }

#undef BAR_
#undef VMCNT4_
#undef STAGE_
#undef LDA_
#undef LDB_
#undef MFMA_

    // ---- epilogue ----
#pragma unroll
    for (int m = 0; m < 8; ++m)
#pragma unroll
        for (int n = 0; n < 4; ++n)
#pragma unroll
            for (int r = 0; r < 4; ++r) {
                int row = bm * 256 + wm * 128 + m * 16 + lq * 4 + r;
                int col = bn * 256 + wn * 64 + n * 16 + lr;
                float v = acc[m][n][r];
                if constexpr (std::is_same_v<OutT, short>)
                    C[(long)row * N + col] = f2bf(v);
                else
                    C[(long)row * N + col] = v;
            }
}

// ---------------- fast-weight scan (MFMA bf16) ----------------
#define SW(row, s) ((row) * 72 + ((((s) >> 3) ^ (((row) >> 4) & 7)) << 3) + ((s) & 7))

__global__ void __launch_bounds__(256)
fastweight(const short* __restrict__ qkv, short* __restrict__ out1, short* __restrict__ out2) {
    const int bid = blockIdx.x;
    const int mem = bid & 1, h = (bid >> 1) & 15, b = bid >> 5;
    const int tid = threadIdx.x;
    const int w = tid >> 6, lane = tid & 63;
    const int lq = lane >> 4, lr = lane & 15;
    __shared__ __align__(16) short sq[64 * 72];
    __shared__ __align__(16) short skS[64 * 72];   // k rows, then S overwrites
    __shared__ __align__(16) short skT[64 * 72];
    __shared__ __align__(16) short svT[64 * 72];
    __shared__ __align__(16) short sWT[64 * 72];
    short* outbuf = mem ? out2 : out1;
    const int koff = 64 + mem * 64;

    for (int i = tid; i < 64 * 36; i += 256) ((int*)sWT)[i] = 0;

    const int r = tid >> 2, seg = (tid & 3) * 16;

    v4f wacc[4] = {};   // persistent W^T slice

    for (int c = 0; c < 4; c++) {
        __syncthreads();
        const long gbase = ((long)((c * 64 + r) * 64 + b)) * 4096 + h * 256;
        {   // q: phi, row-major
            union { int4 v[2]; short s[16]; } u;
            u.v[0] = *(const int4*)(qkv + gbase + seg);
            u.v[1] = *(const int4*)(qkv + gbase + seg + 8);
            float f[16]; float ssum = 0.f;
#pragma unroll
            for (int i = 0; i < 16; i++) {
                float x = bf2f(u.s[i]);
                float e = x > 0.f ? x + 1.f : __expf(x);
                f[i] = e; ssum += e;
            }
            ssum += __shfl_xor(ssum, 1, 64);
            ssum += __shfl_xor(ssum, 2, 64);
            float inv = 1.f / ssum;
            union { int4 v[2]; short s[16]; } o;
#pragma unroll
            for (int i = 0; i < 16; i++) o.s[i] = f2bf(f[i] * inv);
            *(int4*)&sq[SW(r, seg)] = o.v[0];
            *(int4*)&sq[SW(r, seg + 8)] = o.v[1];
        }
        {   // k: phi, row-major + transposed
            union { int4 v[2]; short s[16]; } u;
            u.v[0] = *(const int4*)(qkv + gbase + koff + seg);
            u.v[1] = *(const int4*)(qkv + gbase + koff + seg + 8);
            float f[16]; float ssum = 0.f;
#pragma unroll
            for (int i = 0; i < 16; i++) {
                float x = bf2f(u.s[i]);
                float e = x > 0.f ? x + 1.f : __expf(x);
                f[i] = e; ssum += e;
            }
            ssum += __shfl_xor(ssum, 1, 64);
            ssum += __shfl_xor(ssum, 2, 64);
            float inv = 1.f / ssum;
            union { int4 v[2]; short s[16]; } o;
#pragma unroll
            for (int i = 0; i < 16; i++) o.s[i] = f2bf(f[i] * inv);
            *(int4*)&skS[SW(r, seg)] = o.v[0];
            *(int4*)&skS[SW(r, seg + 8)] = o.v[1];
#pragma unroll
            for (int i = 0; i < 16; i++) skT[SW(seg + i, r)] = o.s[i];
        }
        {   // v: transposed only
            union { int4 v[2]; short s[16]; } u;
            u.v[0] = *(const int4*)(qkv + gbase + 192 + seg);
            u.v[1] = *(const int4*)(qkv + gbase + 192 + seg + 8);
#pragma unroll
            for (int i = 0; i < 16; i++) svT[SW(seg + i, r)] = u.s[i];
        }
        __syncthreads();

        v8s qa0 = *(const v8s*)&sq[SW(16 * w + lr, lq * 8)];
        v8s qa1 = *(const v8s*)&sq[SW(16 * w + lr, 32 + lq * 8)];

        // ---- S = q k^T ----
        v4f sacc[4];
#pragma unroll
        for (int n = 0; n < 4; n++) {
            v8s b0 = *(const v8s*)&skS[SW(16 * n + lr, lq * 8)];
            v8s b1 = *(const v8s*)&skS[SW(16 * n + lr, 32 + lq * 8)];
            v4f t = {};
            t = __builtin_amdgcn_mfma_f32_16x16x32_bf16(qa0, b0, t, 0, 0, 0);
            t = __builtin_amdgcn_mfma_f32_16x16x32_bf16(qa1, b1, t, 0, 0, 0);
            sacc[n] = t;
        }
        __syncthreads();
#pragma unroll
        for (int n = 0; n < 4; n++)
#pragma unroll
            for (int rr = 0; rr < 4; rr++) {
                int t_ = 16 * w + lq * 4 + rr;
                int s_ = 16 * n + lr;
                skS[SW(t_, s_)] = f2bf(s_ <= t_ ? sacc[n][rr] : 0.f);
            }

        // ---- O = S v + q W ----
        v8s sa0 = *(const v8s*)&skS[SW(16 * w + lr, lq * 8)];
        v8s sa1 = *(const v8s*)&skS[SW(16 * w + lr, 32 + lq * 8)];
        v4f oacc[4];
#pragma unroll
        for (int n = 0; n < 4; n++) {
            v8s vb0 = *(const v8s*)&svT[SW(16 * n + lr, lq * 8)];
            v8s vb1 = *(const v8s*)&svT[SW(16 * n + lr, 32 + lq * 8)];
            v8s wb0 = *(const v8s*)&sWT[SW(16 * n + lr, lq * 8)];
            v8s wb1 = *(const v8s*)&sWT[SW(16 * n + lr, 32 + lq * 8)];
            v4f t = {};
            t = __builtin_amdgcn_mfma_f32_16x16x32_bf16(sa0, vb0, t, 0, 0, 0);
            t = __builtin_amdgcn_mfma_f32_16x16x32_bf16(sa1, vb1, t, 0, 0, 0);
            t = __builtin_amdgcn_mfma_f32_16x16x32_bf16(qa0, wb0, t, 0, 0, 0);
            t = __builtin_amdgcn_mfma_f32_16x16x32_bf16(qa1, wb1, t, 0, 0, 0);
            oacc[n] = t;
        }
#pragma unroll
        for (int n = 0; n < 4; n++)
#pragma unroll
            for (int rr = 0; rr < 4; rr++) {
                int t_ = 16 * w + lq * 4 + rr;
                long o = ((long)((c * 64 + t_) * 64 + b)) * 1024 + h * 64 + 16 * n + lr;
                outbuf[o] = f2bf(oacc[n][rr]);
            }

        if (c < 3) {
            __syncthreads();
            // ---- W^T += v^T k ----
            v8s va0 = *(const v8s*)&svT[SW(16 * w + lr, lq * 8)];
            v8s va1 = *(const v8s*)&svT[SW(16 * w + lr, 32 + lq * 8)];
#pragma unroll
            for (int n = 0; n < 4; n++) {
                v8s kb0 = *(const v8s*)&skT[SW(16 * n + lr, lq * 8)];
                v8s kb1 = *(const v8s*)&skT[SW(16 * n + lr, 32 + lq * 8)];
                wacc[n] = __builtin_amdgcn_mfma_f32_16x16x32_bf16(va0, kb0, wacc[n], 0, 0, 0);
                wacc[n] = __builtin_amdgcn_mfma_f32_16x16x32_bf16(va1, kb1, wacc[n], 0, 0, 0);
            }
#pragma unroll
            for (int n = 0; n < 4; n++)
#pragma unroll
                for (int rr = 0; rr < 4; rr++)
                    sWT[SW(16 * w + lq * 4 + rr, 16 * n + lr)] = f2bf(wacc[n][rr]);
        }
    }
}

// ---------------- pi0 mixture: lmix = SCALE*(p*l1 + (1-p)*l2), bf16 x8 ----------------
__global__ void __launch_bounds__(256)
mix_kernel(const short* __restrict__ l1, const short* __restrict__ l2,
           const float* __restrict__ pi0, short* __restrict__ outm) {
    long idx8 = ((long)blockIdx.x * 256 + threadIdx.x) * 8;
    int col = (int)(idx8 & 1023);
    int row = (int)(idx8 >> 10);
    int hh = col >> 6;
    int l = row >> 6;   // row = l*B + b, B=64
    float p = pi0[hh * 256 + l];
    p = fminf(fmaxf(p, 0.f), 1.f);
    float q = 1.f - p;
    union { int4 v; short s[8]; } ua, ub, uo;
    ua.v = *(const int4*)(l1 + idx8);
    ub.v = *(const int4*)(l2 + idx8);
#pragma unroll
    for (int i = 0; i < 8; i++)
        uo.s[i] = f2bf(0.125f * (p * bf2f(ua.s[i]) + q * bf2f(ub.s[i])));
    *(int4*)(outm + idx8) = uo.v;
}

// ---------------- residual + LayerNorm over DM=1024 ----------------
__global__ void __launch_bounds__(256)
ln_kernel(const float* __restrict__ h, const float* __restrict__ attn,
          const float* __restrict__ gamma, const float* __restrict__ beta,
          float* __restrict__ out) {
    const int row = blockIdx.x;
    const long base = (long)row * 1024;
    const int tid = threadIdx.x;
    float4 xh = ((const float4*)(h + base))[tid];
    float4 xa = ((const float4*)(attn + base))[tid];
    float4 x;
    x.x = xh.x + xa.x; x.y = xh.y + xa.y; x.z = xh.z + xa.z; x.w = xh.w + xa.w;
    float s = x.x + x.y + x.z + x.w;
    float s2 = x.x * x.x + x.y * x.y + x.z * x.z + x.w * x.w;
#pragma unroll
    for (int m = 32; m > 0; m >>= 1) {
        s += __shfl_xor(s, m, 64);
        s2 += __shfl_xor(s2, m, 64);
    }
    __shared__ float ps[4], ps2[4];
    int w = tid >> 6, lane = tid & 63;
    if (lane == 0) { ps[w] = s; ps2[w] = s2; }
    __syncthreads();
    s = ps[0] + ps[1] + ps[2] + ps[3];
    s2 = ps2[0] + ps2[1] + ps2[2] + ps2[3];
    float mu = s * (1.f / 1024.f);
    float var = s2 * (1.f / 1024.f) - mu * mu;
    float inv = rsqrtf(var + 1e-5f);
    float4 g = ((const float4*)gamma)[tid];
    float4 bb = ((const float4*)beta)[tid];
    float4 o;
    o.x = (x.x - mu) * inv * g.x + bb.x;
    o.y = (x.y - mu) * inv * g.y + bb.y;
    o.z = (x.z - mu) * inv * g.z + bb.z;
    o.w = (x.w - mu) * inv * g.w + bb.w;
    ((float4*)(out + base))[tid] = o;
}

extern "C" void kernel_launch(void* const* d_in, const int* in_sizes, int n_in,
                              void* d_out, int out_size, void* d_ws, size_t ws_size,
                              hipStream_t stream) {
    const float* h     = (const float*)d_in[0];
    const float* qkvw  = (const float*)d_in[1];
    const float* ow    = (const float*)d_in[2];
    const float* gamma = (const float*)d_in[3];
    const float* beta  = (const float*)d_in[4];
    const float* pi0   = (const float*)d_in[5];
    float* out = (float*)d_out;
    char* ws = (char*)d_ws;

    short* h_bf   = (short*)(ws);                 // 32MB; reused later as layer_mix
    short* wq_bf  = (short*)(ws + 33554432);      // 8MB
    short* wo_bf  = (short*)(ws + 41943040);      // 2MB
    short* qkv_bf = (short*)(ws + 44040192);      // 128MB; reused later as attn f32 (64MB)
    short* l1     = (short*)(ws + 178257920);     // 32MB
    short* l2     = (short*)(ws + 211812352);     // 32MB
    float* attnf  = (float*)(ws + 44040192);
    short* lmix   = h_bf;

    cvt_bf16<<<16384, 256, 0, stream>>>(h, h_bf, 16777216 / 4);
    cvt_bf16<<<4096, 256, 0, stream>>>(qkvw, wq_bf, 4194304 / 4);
    cvt_bf16<<<1024, 256, 0, stream>>>(ow, wo_bf, 1048576 / 4);

    gemm_nt<short><<<dim3(64, 16), 512, 0, stream>>>(h_bf, wq_bf, qkv_bf, 16384, 4096, 1024);

    fastweight<<<2048, 256, 0, stream>>>(qkv_bf, l1, l2);

    mix_kernel<<<8192, 256, 0, stream>>>(l1, l2, pi0, lmix);

    gemm_nt<float><<<dim3(64, 4), 512, 0, stream>>>(lmix, wo_bf, attnf, 16384, 1024, 1024);

    ln_kernel<<<16384, 256, 0, stream>>>(h, attnf, gamma, beta, out);
}